// Round 1
// baseline (17730.284 us; speedup 1.0000x reference)
//
#include <hip/hip_runtime.h>
#include <hip/hip_bf16.h>
#include <stdint.h>

#define T_STEPS 512
#define BATCH   128
#define IN      512
#define HID     1024
#define OUTN    256

typedef __bf16 bf16x8 __attribute__((ext_vector_type(8)));
typedef float  f32x4  __attribute__((ext_vector_type(4)));
typedef unsigned short us8 __attribute__((ext_vector_type(8)));
typedef unsigned int   ui4 __attribute__((ext_vector_type(4)));

__device__ __forceinline__ unsigned short f2bf(float f) {
    uint32_t u = __float_as_uint(f);
    uint32_t r = (u + 0x7fffu + ((u >> 16) & 1u)) >> 16;   // RNE
    return (unsigned short)r;
}

// Swizzled LDS fragment load: 16B at row*stride + (kbyte ^ ((row&7)<<4))
__device__ __forceinline__ bf16x8 ld_frag(const unsigned short* smem, int row, int kbyte, int rowstride) {
    int off = row * rowstride + (kbyte ^ ((row & 7) << 4));
    return *reinterpret_cast<const bf16x8*>(reinterpret_cast<const char*>(smem) + off);
}

__global__ __launch_bounds__(256, 1) void rnn_persistent(
    const float* __restrict__ seqs, const float* __restrict__ W_ih,
    const float* __restrict__ W_hh, const float* __restrict__ b_ih,
    const float* __restrict__ b_hh, const float* __restrict__ W_fc,
    const float* __restrict__ b_fc, float* __restrict__ out,
    unsigned short* __restrict__ hbuf,   // [2][128][1024] bf16
    float* __restrict__ hfinal,          // [128][1024] fp32
    unsigned int* __restrict__ arrive)   // [8][512], zeroed before launch
{
    const int tid  = threadIdx.x;
    const int lane = tid & 63;
    const int wv   = tid >> 6;          // wave 0..3 (K-split)
    const int wg   = blockIdx.x;
    const int g    = wg >> 5;           // batch group 0..7 (rows g*16..+15)
    const int w    = wg & 31;           // col slice (cols w*32..+31)
    const int gr0  = g * 16;
    const int c0   = w * 32;
    const int ln15 = lane & 15;
    const int lk   = lane >> 4;

    __shared__ unsigned short xtile[16 * 512];   // 16KB, swizzled bf16
    __shared__ unsigned short htile[16 * 1024];  // 32KB, swizzled bf16
    __shared__ float red[4][16][33];             // wave partials (+1 pad)
    __shared__ float biasS[32];

    // ---- init: weight B-fragments into registers (bf16) ----
    bf16x8 wih[2][4];
    bf16x8 whh[2][8];
    #pragma unroll
    for (int nt = 0; nt < 2; nt++) {
        const int j = c0 + nt * 16 + ln15;
        #pragma unroll
        for (int s = 0; s < 4; s++) {
            const int k = wv * 128 + s * 32 + lk * 8;
            const float* p = W_ih + j * IN + k;
            us8 u;
            #pragma unroll
            for (int e = 0; e < 8; e++) u[e] = f2bf(p[e]);
            wih[nt][s] = __builtin_bit_cast(bf16x8, u);
        }
        #pragma unroll
        for (int s = 0; s < 8; s++) {
            const int k = wv * 256 + s * 32 + lk * 8;
            const float* p = W_hh + j * HID + k;
            us8 u;
            #pragma unroll
            for (int e = 0; e < 8; e++) u[e] = f2bf(p[e]);
            whh[nt][s] = __builtin_bit_cast(bf16x8, u);
        }
    }
    if (tid < 32) biasS[tid] = b_ih[c0 + tid] + b_hh[c0 + tid];
    __syncthreads();

    unsigned int* arr = arrive + g * T_STEPS;

    for (int t = 0; t < T_STEPS; t++) {
        // ---- stage x_t: global fp32 -> LDS bf16 (swizzled) ----
        {
            const float* src = seqs + (size_t)t * (BATCH * IN) + (size_t)gr0 * IN;
            #pragma unroll
            for (int it = 0; it < 4; it++) {
                const int c    = tid + it * 256;     // 16B chunk id
                const int row  = c >> 6;             // 64 chunks/row
                const int colc = c & 63;
                const float* s4 = src + row * IN + colc * 8;
                float4 a = *reinterpret_cast<const float4*>(s4);
                float4 b = *reinterpret_cast<const float4*>(s4 + 4);
                us8 u;
                u[0]=f2bf(a.x); u[1]=f2bf(a.y); u[2]=f2bf(a.z); u[3]=f2bf(a.w);
                u[4]=f2bf(b.x); u[5]=f2bf(b.y); u[6]=f2bf(b.z); u[7]=f2bf(b.w);
                const int off = row * 1024 + ((colc * 16) ^ ((row & 7) << 4));
                *reinterpret_cast<us8*>(reinterpret_cast<char*>(xtile) + off) = u;
            }
        }
        __syncthreads();

        f32x4 acc0 = {0.f, 0.f, 0.f, 0.f};
        f32x4 acc1 = {0.f, 0.f, 0.f, 0.f};

        // ---- input projection MFMAs (h-independent; overlaps others' step t-1) ----
        {
            const int kx0b = wv * 256;  // wave K-slice base, bytes
            #pragma unroll
            for (int s = 0; s < 4; s++) {
                bf16x8 a = ld_frag(xtile, ln15, kx0b + s * 64 + lk * 16, 1024);
                acc0 = __builtin_amdgcn_mfma_f32_16x16x32_bf16(a, wih[0][s], acc0, 0, 0, 0);
                acc1 = __builtin_amdgcn_mfma_f32_16x16x32_bf16(a, wih[1][s], acc1, 0, 0, 0);
            }
        }

        if (t > 0) {
            // ---- wait: all 32 WGs of this group finished step t-1 ----
            if (tid == 0) {
                while (__hip_atomic_load(arr + (t - 1), __ATOMIC_RELAXED, __HIP_MEMORY_SCOPE_AGENT) < 32u) {
                    __builtin_amdgcn_s_sleep(1);
                }
            }
            __syncthreads();
            __threadfence();   // acquire: invalidate caches before reading others' h

            // ---- stage h_t: global bf16 -> LDS (swizzled) ----
            const unsigned short* hsrc = hbuf + (size_t)(t & 1) * (BATCH * HID) + (size_t)gr0 * HID;
            #pragma unroll
            for (int it = 0; it < 8; it++) {
                const int c    = tid + it * 256;
                const int row  = c >> 7;             // 128 chunks/row
                const int colc = c & 127;
                ui4 v = *reinterpret_cast<const ui4*>(hsrc + row * HID + colc * 8);
                const int off = row * 2048 + ((colc * 16) ^ ((row & 7) << 4));
                *reinterpret_cast<ui4*>(reinterpret_cast<char*>(htile) + off) = v;
            }
            __syncthreads();

            // ---- recurrence MFMAs ----
            const int kh0b = wv * 512;
            #pragma unroll
            for (int s = 0; s < 8; s++) {
                bf16x8 a = ld_frag(htile, ln15, kh0b + s * 64 + lk * 16, 2048);
                acc0 = __builtin_amdgcn_mfma_f32_16x16x32_bf16(a, whh[0][s], acc0, 0, 0, 0);
                acc1 = __builtin_amdgcn_mfma_f32_16x16x32_bf16(a, whh[1][s], acc1, 0, 0, 0);
            }
        }

        // ---- cross-wave K-reduction ----
        #pragma unroll
        for (int r = 0; r < 4; r++) {
            red[wv][lk * 4 + r][ln15]      = acc0[r];
            red[wv][lk * 4 + r][16 + ln15] = acc1[r];
        }
        __syncthreads();
        {
            const int ro = tid >> 5;    // 0..7
            const int co = tid & 31;
            unsigned short* hdst = hbuf + (size_t)((t + 1) & 1) * (BATCH * HID);
            #pragma unroll
            for (int hh2 = 0; hh2 < 2; hh2++) {
                const int row = ro + hh2 * 8;
                float v = red[0][row][co] + red[1][row][co] + red[2][row][co]
                        + red[3][row][co] + biasS[co];
                v = fmaxf(v, 0.0f);
                hdst[(size_t)(gr0 + row) * HID + c0 + co] = f2bf(v);
                if (t == T_STEPS - 1) hfinal[(size_t)(gr0 + row) * HID + c0 + co] = v;
            }
        }
        __syncthreads();              // all stores issued+drained before signal
        if (tid == 0) {
            __threadfence();          // release
            atomicAdd(arr + t, 1u);
        }
    }

    // ---- final group barrier, then fused FC: out = hfinal @ W_fc^T + b_fc ----
    if (tid == 0) {
        while (__hip_atomic_load(arr + (T_STEPS - 1), __ATOMIC_RELAXED, __HIP_MEMORY_SCOPE_AGENT) < 32u) {
            __builtin_amdgcn_s_sleep(1);
        }
    }
    __syncthreads();
    __threadfence();

    {
        // WG computes out[gr0..gr0+15][w*8..w*8+7]; 2-way K-split over 256 threads
        const int oi   = tid & 127;
        const int half = tid >> 7;
        const int brow = gr0 + (oi >> 3);
        const int o    = w * 8 + (oi & 7);
        const float* hv = hfinal + (size_t)brow * HID + half * 512;
        const float* wf = W_fc  + (size_t)o * HID + half * 512;
        float sum = 0.f;
        #pragma unroll 4
        for (int k = 0; k < 512; k += 4) {
            float4 hh = *reinterpret_cast<const float4*>(hv + k);
            float4 ww = *reinterpret_cast<const float4*>(wf + k);
            sum += hh.x * ww.x + hh.y * ww.y + hh.z * ww.z + hh.w * ww.w;
        }
        float* redf = &red[0][0][0];
        redf[tid] = sum;
        __syncthreads();
        if (tid < 128) {
            out[(size_t)brow * OUTN + o] = redf[tid] + redf[tid + 128] + b_fc[o];
        }
    }
}

extern "C" void kernel_launch(void* const* d_in, const int* in_sizes, int n_in,
                              void* d_out, int out_size, void* d_ws, size_t ws_size,
                              hipStream_t stream) {
    const float* seqs = (const float*)d_in[0];
    const float* W_ih = (const float*)d_in[1];
    const float* W_hh = (const float*)d_in[2];
    const float* b_ih = (const float*)d_in[3];
    const float* b_hh = (const float*)d_in[4];
    const float* W_fc = (const float*)d_in[5];
    const float* b_fc = (const float*)d_in[6];
    float* out = (float*)d_out;

    char* ws = (char*)d_ws;
    unsigned short* hbuf   = (unsigned short*)ws;                 // 2*128*1024*2 = 524288 B
    float*          hfinal = (float*)(ws + 524288);               // 128*1024*4   = 524288 B
    unsigned int*   arrive = (unsigned int*)(ws + 1048576);       // 8*512*4      = 16384 B

    hipMemsetAsync(arrive, 0, 8 * T_STEPS * sizeof(unsigned int), stream);
    rnn_persistent<<<dim3(256), dim3(256), 0, stream>>>(
        seqs, W_ih, W_hh, b_ih, b_hh, W_fc, b_fc, out, hbuf, hfinal, arrive);
}

// Round 2
// 3028.384 us; speedup vs baseline: 5.8547x; 5.8547x over previous
//
#include <hip/hip_runtime.h>
#include <hip/hip_bf16.h>
#include <stdint.h>

#define T_STEPS 512
#define BATCH   128
#define IN      512
#define HID     1024
#define OUTN    256

typedef __bf16 bf16x8 __attribute__((ext_vector_type(8)));
typedef float  f32x4  __attribute__((ext_vector_type(4)));
typedef unsigned short us8 __attribute__((ext_vector_type(8)));

__device__ __forceinline__ unsigned short f2bf(float f) {
    uint32_t u = __float_as_uint(f);
    uint32_t r = (u + 0x7fffu + ((u >> 16) & 1u)) >> 16;   // RNE
    return (unsigned short)r;
}

// Swizzled LDS fragment load: 16B at row*stride + (kbyte ^ ((row&7)<<4))
__device__ __forceinline__ bf16x8 ld_frag(const unsigned short* smem, int row, int kbyte, int rowstride) {
    int off = row * rowstride + (kbyte ^ ((row & 7) << 4));
    return *reinterpret_cast<const bf16x8*>(reinterpret_cast<const char*>(smem) + off);
}

__global__ __launch_bounds__(256, 1) void rnn_persistent(
    const float* __restrict__ seqs, const float* __restrict__ W_ih,
    const float* __restrict__ W_hh, const float* __restrict__ b_ih,
    const float* __restrict__ b_hh, const float* __restrict__ W_fc,
    const float* __restrict__ b_fc, float* __restrict__ out,
    unsigned short* __restrict__ hbuf,   // [2][128][1024] bf16
    float* __restrict__ hfinal,          // [128][1024] fp32
    unsigned int* __restrict__ flags)    // [8][32] steps-completed per WG, zeroed
{
    const int tid  = threadIdx.x;
    const int lane = tid & 63;
    const int wv   = tid >> 6;          // wave 0..3 (K-split)
    const int wg   = blockIdx.x;
    const int g    = wg >> 5;           // batch group 0..7 (rows g*16..+15)
    const int w    = wg & 31;           // col slice (cols w*32..+31)
    const int gr0  = g * 16;
    const int c0   = w * 32;
    const int ln15 = lane & 15;
    const int lk   = lane >> 4;

    __shared__ unsigned short xtile[16 * 512];   // 16KB, swizzled bf16
    __shared__ unsigned short htile[16 * 1024];  // 32KB, swizzled bf16
    __shared__ float red[4][16][33];             // wave partials (+1 pad)
    __shared__ float biasS[32];

    // ---- init: weight B-fragments into registers (bf16) ----
    bf16x8 wih[2][4];
    bf16x8 whh[2][8];
    #pragma unroll
    for (int nt = 0; nt < 2; nt++) {
        const int j = c0 + nt * 16 + ln15;
        #pragma unroll
        for (int s = 0; s < 4; s++) {
            const int k = wv * 128 + s * 32 + lk * 8;
            const float* p = W_ih + j * IN + k;
            us8 u;
            #pragma unroll
            for (int e = 0; e < 8; e++) u[e] = f2bf(p[e]);
            wih[nt][s] = __builtin_bit_cast(bf16x8, u);
        }
        #pragma unroll
        for (int s = 0; s < 8; s++) {
            const int k = wv * 256 + s * 32 + lk * 8;
            const float* p = W_hh + j * HID + k;
            us8 u;
            #pragma unroll
            for (int e = 0; e < 8; e++) u[e] = f2bf(p[e]);
            whh[nt][s] = __builtin_bit_cast(bf16x8, u);
        }
    }
    if (tid < 32) biasS[tid] = b_ih[c0 + tid] + b_hh[c0 + tid];
    __syncthreads();

    unsigned int* grp_flags = flags + g * 32;
    unsigned int* my_flag   = grp_flags + w;

    for (int t = 0; t < T_STEPS; t++) {
        // ---- stage x_t: global fp32 -> LDS bf16 (swizzled) ----
        {
            const float* src = seqs + (size_t)t * (BATCH * IN) + (size_t)gr0 * IN;
            #pragma unroll
            for (int it = 0; it < 4; it++) {
                const int c    = tid + it * 256;     // 16B chunk id
                const int row  = c >> 6;             // 64 chunks/row
                const int colc = c & 63;
                const float* s4 = src + row * IN + colc * 8;
                float4 a = *reinterpret_cast<const float4*>(s4);
                float4 b = *reinterpret_cast<const float4*>(s4 + 4);
                us8 u;
                u[0]=f2bf(a.x); u[1]=f2bf(a.y); u[2]=f2bf(a.z); u[3]=f2bf(a.w);
                u[4]=f2bf(b.x); u[5]=f2bf(b.y); u[6]=f2bf(b.z); u[7]=f2bf(b.w);
                const int off = row * 1024 + ((colc * 16) ^ ((row & 7) << 4));
                *reinterpret_cast<us8*>(reinterpret_cast<char*>(xtile) + off) = u;
            }
        }
        __syncthreads();

        f32x4 acc0 = {0.f, 0.f, 0.f, 0.f};
        f32x4 acc1 = {0.f, 0.f, 0.f, 0.f};

        // ---- input projection MFMAs (h-independent; overlaps others' step t-1) ----
        {
            const int kx0b = wv * 256;  // wave K-slice base, bytes
            #pragma unroll
            for (int s = 0; s < 4; s++) {
                bf16x8 a = ld_frag(xtile, ln15, kx0b + s * 64 + lk * 16, 1024);
                acc0 = __builtin_amdgcn_mfma_f32_16x16x32_bf16(a, wih[0][s], acc0, 0, 0, 0);
                acc1 = __builtin_amdgcn_mfma_f32_16x16x32_bf16(a, wih[1][s], acc1, 0, 0, 0);
            }
        }

        if (t > 0) {
            // ---- wait: all 32 WGs of this group finished step t-1 (parallel flag spin) ----
            if (tid < 32) {
                const unsigned int* f = grp_flags + tid;
                while (__hip_atomic_load(f, __ATOMIC_RELAXED, __HIP_MEMORY_SCOPE_AGENT) < (unsigned)t) {
                    __builtin_amdgcn_s_sleep(1);
                }
            }
            __syncthreads();   // all waves see: step t-1 data is at LLC (sc1 loads below)

            // ---- stage h_t: LLC bf16 -> LDS (swizzled), agent-scope loads ----
            const unsigned long long* hsrc = reinterpret_cast<const unsigned long long*>(
                hbuf + (size_t)(t & 1) * (BATCH * HID) + (size_t)gr0 * HID);
            #pragma unroll
            for (int it = 0; it < 16; it++) {
                const int c    = tid + it * 256;     // 8B chunk id, 256 per row
                const int row  = c >> 8;
                const int colc = c & 255;
                unsigned long long v = __hip_atomic_load(hsrc + row * 256 + colc,
                                                         __ATOMIC_RELAXED, __HIP_MEMORY_SCOPE_AGENT);
                const int off = row * 2048 + ((colc * 8) ^ ((row & 7) << 4));
                *reinterpret_cast<unsigned long long*>(reinterpret_cast<char*>(htile) + off) = v;
            }
            __syncthreads();

            // ---- recurrence MFMAs ----
            const int kh0b = wv * 512;
            #pragma unroll
            for (int s = 0; s < 8; s++) {
                bf16x8 a = ld_frag(htile, ln15, kh0b + s * 64 + lk * 16, 2048);
                acc0 = __builtin_amdgcn_mfma_f32_16x16x32_bf16(a, whh[0][s], acc0, 0, 0, 0);
                acc1 = __builtin_amdgcn_mfma_f32_16x16x32_bf16(a, whh[1][s], acc1, 0, 0, 0);
            }
        }

        // ---- cross-wave K-reduction ----
        #pragma unroll
        for (int r = 0; r < 4; r++) {
            red[wv][lk * 4 + r][ln15]      = acc0[r];
            red[wv][lk * 4 + r][16 + ln15] = acc1[r];
        }
        __syncthreads();
        {
            const int row = tid >> 4;          // 0..15
            const int co2 = (tid & 15) * 2;    // even col within slice
            float v0 = red[0][row][co2]   + red[1][row][co2]   + red[2][row][co2]   + red[3][row][co2]   + biasS[co2];
            float v1 = red[0][row][co2+1] + red[1][row][co2+1] + red[2][row][co2+1] + red[3][row][co2+1] + biasS[co2+1];
            v0 = fmaxf(v0, 0.0f);
            v1 = fmaxf(v1, 0.0f);
            if (t < T_STEPS - 1) {
                unsigned int pack = (unsigned)f2bf(v0) | ((unsigned)f2bf(v1) << 16);
                unsigned int* dst = reinterpret_cast<unsigned int*>(
                    hbuf + (size_t)((t + 1) & 1) * (BATCH * HID) + (size_t)(gr0 + row) * HID + c0 + co2);
                __hip_atomic_store(dst, pack, __ATOMIC_RELAXED, __HIP_MEMORY_SCOPE_AGENT);
            } else {
                unsigned long long pack = ((unsigned long long)__float_as_uint(v1) << 32) | __float_as_uint(v0);
                unsigned long long* dst = reinterpret_cast<unsigned long long*>(
                    hfinal + (size_t)(gr0 + row) * HID + c0 + co2);
                __hip_atomic_store(dst, pack, __ATOMIC_RELAXED, __HIP_MEMORY_SCOPE_AGENT);
            }
        }
        asm volatile("s_waitcnt vmcnt(0)" ::: "memory");  // our sc1 stores acked at LLC
        __syncthreads();                                   // every thread's store drained
        if (tid == 0) {
            __hip_atomic_store(my_flag, (unsigned)(t + 1), __ATOMIC_RELAXED, __HIP_MEMORY_SCOPE_AGENT);
        }
    }

    // ---- final group barrier, then fused FC: out = hfinal @ W_fc^T + b_fc ----
    if (tid < 32) {
        const unsigned int* f = grp_flags + tid;
        while (__hip_atomic_load(f, __ATOMIC_RELAXED, __HIP_MEMORY_SCOPE_AGENT) < (unsigned)T_STEPS) {
            __builtin_amdgcn_s_sleep(1);
        }
    }
    __syncthreads();
    __threadfence();   // once: invalidate L1/L2 so plain float4 loads below see LLC data

    {
        // WG computes out[gr0..gr0+15][w*8..w*8+7]; 2-way K-split over 256 threads
        const int oi   = tid & 127;
        const int half = tid >> 7;
        const int brow = gr0 + (oi >> 3);
        const int o    = w * 8 + (oi & 7);
        const float* hv = hfinal + (size_t)brow * HID + half * 512;
        const float* wf = W_fc  + (size_t)o * HID + half * 512;
        float sum = 0.f;
        #pragma unroll 4
        for (int k = 0; k < 512; k += 4) {
            float4 hh = *reinterpret_cast<const float4*>(hv + k);
            float4 ww = *reinterpret_cast<const float4*>(wf + k);
            sum += hh.x * ww.x + hh.y * ww.y + hh.z * ww.z + hh.w * ww.w;
        }
        float* redf = &red[0][0][0];
        redf[tid] = sum;
        __syncthreads();
        if (tid < 128) {
            out[(size_t)brow * OUTN + o] = redf[tid] + redf[tid + 128] + b_fc[o];
        }
    }
}

extern "C" void kernel_launch(void* const* d_in, const int* in_sizes, int n_in,
                              void* d_out, int out_size, void* d_ws, size_t ws_size,
                              hipStream_t stream) {
    const float* seqs = (const float*)d_in[0];
    const float* W_ih = (const float*)d_in[1];
    const float* W_hh = (const float*)d_in[2];
    const float* b_ih = (const float*)d_in[3];
    const float* b_hh = (const float*)d_in[4];
    const float* W_fc = (const float*)d_in[5];
    const float* b_fc = (const float*)d_in[6];
    float* out = (float*)d_out;

    char* ws = (char*)d_ws;
    unsigned short* hbuf   = (unsigned short*)ws;                 // 2*128*1024*2 = 524288 B
    float*          hfinal = (float*)(ws + 524288);               // 128*1024*4   = 524288 B
    unsigned int*   flags  = (unsigned int*)(ws + 1048576);       // 8*32*4       = 1024 B

    hipMemsetAsync(flags, 0, 8 * 32 * sizeof(unsigned int), stream);
    rnn_persistent<<<dim3(256), dim3(256), 0, stream>>>(
        seqs, W_ih, W_hh, b_ih, b_hh, W_fc, b_fc, out, hbuf, hfinal, flags);
}

// Round 4
// 1395.580 us; speedup vs baseline: 12.7046x; 2.1700x over previous
//
#include <hip/hip_runtime.h>
#include <hip/hip_bf16.h>
#include <stdint.h>

#define T_STEPS 512
#define BATCH   128
#define IN      512
#define HID     1024
#define OUTN    256

typedef __bf16 bf16x8 __attribute__((ext_vector_type(8)));
typedef float  f32x4  __attribute__((ext_vector_type(4)));
typedef unsigned short us8 __attribute__((ext_vector_type(8)));
typedef unsigned int   ui4 __attribute__((ext_vector_type(4)));

__device__ __forceinline__ unsigned short f2bf(float f) {
    uint32_t u = __float_as_uint(f);
    uint32_t r = (u + 0x7fffu + ((u >> 16) & 1u)) >> 16;   // RNE
    return (unsigned short)r;
}

// Agent-coherent 16B load: bypass L1+L2 (sc0 sc1), read from LLC. Issue-only;
// completion is claimed by an explicit counted s_waitcnt.
__device__ __forceinline__ ui4 ld_u128_agent(const void* p) {
    ui4 v;
    asm volatile("global_load_dwordx4 %0, %1, off sc0 sc1"
                 : "=v"(v) : "v"(p) : "memory");
    return v;
}

// Swizzled LDS fragment load: 16B at row*stride + (kbyte ^ ((row&7)<<4))
__device__ __forceinline__ bf16x8 ld_frag(const unsigned short* smem, int row, int kbyte, int rowstride) {
    int off = row * rowstride + (kbyte ^ ((row & 7) << 4));
    return *reinterpret_cast<const bf16x8*>(reinterpret_cast<const char*>(smem) + off);
}

__global__ __launch_bounds__(256, 1) void rnn_persistent(
    const float* __restrict__ seqs, const float* __restrict__ W_ih,
    const float* __restrict__ W_hh, const float* __restrict__ b_ih,
    const float* __restrict__ b_hh, const float* __restrict__ W_fc,
    const float* __restrict__ b_fc, float* __restrict__ out,
    unsigned short* __restrict__ hbuf,   // [2][128][1024] bf16
    float* __restrict__ hfinal,          // [128][1024] fp32
    unsigned int* __restrict__ flags)    // [8][32] steps-completed per WG, zeroed
{
    const int tid  = threadIdx.x;
    const int lane = tid & 63;
    const int wv   = tid >> 6;          // wave 0..3 (K-split)
    const int wg   = blockIdx.x;
    const int g    = wg >> 5;           // batch group 0..7 (rows g*16..+15)
    const int w    = wg & 31;           // col slice (cols w*32..+31)
    const int gr0  = g * 16;
    const int c0   = w * 32;
    const int ln15 = lane & 15;
    const int lk   = lane >> 4;

    __shared__ unsigned short xtile[16 * 512];   // 16KB, swizzled bf16
    __shared__ unsigned short htile[16 * 1024];  // 32KB, swizzled bf16
    __shared__ float red[4][16][33];             // wave partials (+1 pad)
    __shared__ float biasS[32];

    // ---- init: weight B-fragments into registers (bf16) ----
    bf16x8 wih[2][4];
    bf16x8 whh[2][8];
    #pragma unroll
    for (int nt = 0; nt < 2; nt++) {
        const int j = c0 + nt * 16 + ln15;
        #pragma unroll
        for (int s = 0; s < 4; s++) {
            const int k = wv * 128 + s * 32 + lk * 8;
            const float* p = W_ih + j * IN + k;
            us8 u;
            #pragma unroll
            for (int e = 0; e < 8; e++) u[e] = f2bf(p[e]);
            wih[nt][s] = __builtin_bit_cast(bf16x8, u);
        }
        #pragma unroll
        for (int s = 0; s < 8; s++) {
            const int k = wv * 256 + s * 32 + lk * 8;
            const float* p = W_hh + j * HID + k;
            us8 u;
            #pragma unroll
            for (int e = 0; e < 8; e++) u[e] = f2bf(p[e]);
            whh[nt][s] = __builtin_bit_cast(bf16x8, u);
        }
    }
    if (tid < 32) biasS[tid] = b_ih[c0 + tid] + b_hh[c0 + tid];

    unsigned int* grp_flags = flags + g * 32;
    unsigned int* my_flag   = grp_flags + w;

    // per-thread x chunk coords (16B chunks, 64 per row)
    const int xrow[4] = { (tid) >> 6, (tid + 256) >> 6, (tid + 512) >> 6, (tid + 768) >> 6 };
    const int xcol[4] = { (tid) & 63, (tid + 256) & 63, (tid + 512) & 63, (tid + 768) & 63 };

    // ---- prologue: load + convert x(0) ----
    us8 xbf[4];
    {
        const float* xsrc = seqs + (size_t)gr0 * IN;
        #pragma unroll
        for (int it = 0; it < 4; it++) {
            const float* s4 = xsrc + xrow[it] * IN + xcol[it] * 8;
            float4 a = *reinterpret_cast<const float4*>(s4);
            float4 b = *reinterpret_cast<const float4*>(s4 + 4);
            us8 u;
            u[0]=f2bf(a.x); u[1]=f2bf(a.y); u[2]=f2bf(a.z); u[3]=f2bf(a.w);
            u[4]=f2bf(b.x); u[5]=f2bf(b.y); u[6]=f2bf(b.z); u[7]=f2bf(b.w);
            xbf[it] = u;
        }
    }

    for (int t = 0; t < T_STEPS; t++) {
        // TOP: write prepared x(t) bf16 regs -> xtile (swizzled)
        #pragma unroll
        for (int it = 0; it < 4; it++) {
            const int off = xrow[it] * 1024 + ((xcol[it] * 16) ^ ((xrow[it] & 7) << 4));
            *reinterpret_cast<us8*>(reinterpret_cast<char*>(xtile) + off) = xbf[it];
        }

        // SPIN: wave0 lanes<32 poll the 32 group flags (agent scope, LLC)
        if (t > 0 && wv == 0 && lane < 32) {
            const unsigned int* f = grp_flags + lane;
            while (__hip_atomic_load(f, __ATOMIC_RELAXED, __HIP_MEMORY_SCOPE_AGENT) < (unsigned)t) {
                __builtin_amdgcn_s_sleep(1);
            }
        }
        __syncthreads();   // xtile visible + h(t) data globally visible

        // D1: issue 8 agent h-loads (oldest 8 vmem ops of this step)
        ui4 hv[8];
        if (t > 0) {
            const char* hsrc = reinterpret_cast<const char*>(
                hbuf + (size_t)(t & 1) * (BATCH * HID) + (size_t)gr0 * HID);
            #pragma unroll
            for (int it = 0; it < 8; it++) {
                const int c    = tid + it * 256;     // 16B chunk id, 128/row
                const int row  = c >> 7;
                const int colc = c & 127;
                hv[it] = ld_u128_agent(hsrc + row * 2048 + colc * 16);
            }
        }

        // A': issue 8 plain x loads for step t+1 (dup-load t at the last step)
        float4 xr[8];
        {
            const int tn = (t + 1 < T_STEPS) ? t + 1 : t;
            const float* xsrc = seqs + (size_t)tn * (BATCH * IN) + (size_t)gr0 * IN;
            #pragma unroll
            for (int it = 0; it < 4; it++) {
                const float* s4 = xsrc + xrow[it] * IN + xcol[it] * 8;
                xr[2*it]   = *reinterpret_cast<const float4*>(s4);
                xr[2*it+1] = *reinterpret_cast<const float4*>(s4 + 4);
            }
        }

        // E1: x-projection MFMAs (overlap the h-load LLC latency)
        f32x4 acc0 = {0.f, 0.f, 0.f, 0.f};
        f32x4 acc1 = {0.f, 0.f, 0.f, 0.f};
        {
            const int kx0b = wv * 256;
            #pragma unroll
            for (int s = 0; s < 4; s++) {
                bf16x8 a = ld_frag(xtile, ln15, kx0b + s * 64 + lk * 16, 1024);
                acc0 = __builtin_amdgcn_mfma_f32_16x16x32_bf16(a, wih[0][s], acc0, 0, 0, 0);
                acc1 = __builtin_amdgcn_mfma_f32_16x16x32_bf16(a, wih[1][s], acc1, 0, 0, 0);
            }
        }

        if (t > 0) {
            // D2: claim ONLY the h loads (8 x loads stay in flight), stage htile
            asm volatile("s_waitcnt vmcnt(8)" ::: "memory");
            __builtin_amdgcn_sched_barrier(0);
            #pragma unroll
            for (int it = 0; it < 8; it++) {
                const int c    = tid + it * 256;
                const int row  = c >> 7;
                const int colc = c & 127;
                const int off = row * 2048 + ((colc * 16) ^ ((row & 7) << 4));
                *reinterpret_cast<ui4*>(reinterpret_cast<char*>(htile) + off) = hv[it];
            }
            __syncthreads();

            // E2: recurrence MFMAs
            const int kh0b = wv * 512;
            #pragma unroll
            for (int s = 0; s < 8; s++) {
                bf16x8 a = ld_frag(htile, ln15, kh0b + s * 64 + lk * 16, 2048);
                acc0 = __builtin_amdgcn_mfma_f32_16x16x32_bf16(a, whh[0][s], acc0, 0, 0, 0);
                acc1 = __builtin_amdgcn_mfma_f32_16x16x32_bf16(a, whh[1][s], acc1, 0, 0, 0);
            }
        }

        // F: cross-wave K-reduction -> relu -> h store
        #pragma unroll
        for (int r = 0; r < 4; r++) {
            red[wv][lk * 4 + r][ln15]      = acc0[r];
            red[wv][lk * 4 + r][16 + ln15] = acc1[r];
        }
        __syncthreads();
        {
            const int row = tid >> 4;          // 0..15
            const int co2 = (tid & 15) * 2;    // even col within slice
            float v0 = red[0][row][co2]   + red[1][row][co2]   + red[2][row][co2]   + red[3][row][co2]   + biasS[co2];
            float v1 = red[0][row][co2+1] + red[1][row][co2+1] + red[2][row][co2+1] + red[3][row][co2+1] + biasS[co2+1];
            v0 = fmaxf(v0, 0.0f);
            v1 = fmaxf(v1, 0.0f);

            // x(t+1) loads are done by now; convert before the store drain
            asm volatile("s_waitcnt vmcnt(0)" ::: "memory");
            __builtin_amdgcn_sched_barrier(0);
            #pragma unroll
            for (int it = 0; it < 4; it++) {
                float4 a = xr[2*it], b = xr[2*it+1];
                us8 u;
                u[0]=f2bf(a.x); u[1]=f2bf(a.y); u[2]=f2bf(a.z); u[3]=f2bf(a.w);
                u[4]=f2bf(b.x); u[5]=f2bf(b.y); u[6]=f2bf(b.z); u[7]=f2bf(b.w);
                xbf[it] = u;
            }

            if (t < T_STEPS - 1) {
                unsigned pack = (unsigned)f2bf(v0) | ((unsigned)f2bf(v1) << 16);
                unsigned* dst = reinterpret_cast<unsigned*>(
                    hbuf + (size_t)((t + 1) & 1) * (BATCH * HID) + (size_t)(gr0 + row) * HID + c0 + co2);
                __hip_atomic_store(dst, pack, __ATOMIC_RELAXED, __HIP_MEMORY_SCOPE_AGENT);
            } else {
                unsigned long long pack = ((unsigned long long)__float_as_uint(v1) << 32) | __float_as_uint(v0);
                unsigned long long* dst = reinterpret_cast<unsigned long long*>(
                    hfinal + (size_t)(gr0 + row) * HID + c0 + co2);
                __hip_atomic_store(dst, pack, __ATOMIC_RELAXED, __HIP_MEMORY_SCOPE_AGENT);
            }
        }
        asm volatile("s_waitcnt vmcnt(0)" ::: "memory");  // h stores acked
        __syncthreads();                                   // every thread drained
        if (tid == 0) {
            __hip_atomic_store(my_flag, (unsigned)(t + 1), __ATOMIC_RELAXED, __HIP_MEMORY_SCOPE_AGENT);
        }
    }

    // ---- final group barrier, then fused FC: out = hfinal @ W_fc^T + b_fc ----
    if (wv == 0 && lane < 32) {
        const unsigned int* f = grp_flags + lane;
        while (__hip_atomic_load(f, __ATOMIC_RELAXED, __HIP_MEMORY_SCOPE_AGENT) < (unsigned)T_STEPS) {
            __builtin_amdgcn_s_sleep(1);
        }
    }
    __syncthreads();
    __threadfence();   // once: see peers' hfinal through plain loads below

    {
        // WG computes out[gr0..gr0+15][w*8..w*8+7]; 2-way K-split over 256 threads
        const int oi   = tid & 127;
        const int half = tid >> 7;
        const int brow = gr0 + (oi >> 3);
        const int o    = w * 8 + (oi & 7);
        const float* hv2 = hfinal + (size_t)brow * HID + half * 512;
        const float* wf  = W_fc  + (size_t)o * HID + half * 512;
        float sum = 0.f;
        #pragma unroll 4
        for (int k = 0; k < 512; k += 4) {
            float4 hh = *reinterpret_cast<const float4*>(hv2 + k);
            float4 ww = *reinterpret_cast<const float4*>(wf + k);
            sum += hh.x * ww.x + hh.y * ww.y + hh.z * ww.z + hh.w * ww.w;
        }
        float* redf = &red[0][0][0];
        redf[tid] = sum;
        __syncthreads();
        if (tid < 128) {
            out[(size_t)brow * OUTN + o] = redf[tid] + redf[tid + 128] + b_fc[o];
        }
    }
}

extern "C" void kernel_launch(void* const* d_in, const int* in_sizes, int n_in,
                              void* d_out, int out_size, void* d_ws, size_t ws_size,
                              hipStream_t stream) {
    const float* seqs = (const float*)d_in[0];
    const float* W_ih = (const float*)d_in[1];
    const float* W_hh = (const float*)d_in[2];
    const float* b_ih = (const float*)d_in[3];
    const float* b_hh = (const float*)d_in[4];
    const float* W_fc = (const float*)d_in[5];
    const float* b_fc = (const float*)d_in[6];
    float* out = (float*)d_out;

    char* ws = (char*)d_ws;
    unsigned short* hbuf   = (unsigned short*)ws;                 // 2*128*1024*2 = 524288 B
    float*          hfinal = (float*)(ws + 524288);               // 128*1024*4   = 524288 B
    unsigned int*   flags  = (unsigned int*)(ws + 1048576);       // 8*32*4       = 1024 B

    hipMemsetAsync(flags, 0, 1024, stream);
    rnn_persistent<<<dim3(256), dim3(256), 0, stream>>>(
        seqs, W_ih, W_hh, b_ih, b_hh, W_fc, b_fc, out, hbuf, hfinal, flags);
}